// Round 1
// baseline (8761.571 us; speedup 1.0000x reference)
//
#include <hip/hip_runtime.h>
#include <hip/hip_bf16.h>

#define Bsz 64
#define Tsz 512
#define Isz 512
#define Hsz 512

// ---------------- Phase 1: xU = x @ U + bias ----------------
// M = B*T = 32768, K = 512, N = 512. Tile 128x64, BK=32, 256 threads, 8x4 micro.
__global__ __launch_bounds__(256) void p1_gemm(const float* __restrict__ X,
                                               const float* __restrict__ U,
                                               const float* __restrict__ bias,
                                               float* __restrict__ out) {
  const int K = Isz, N = Hsz;
  __shared__ float As[32][128];   // [kk][m], 16 KB
  __shared__ float Bs[32][64];    // [kk][n],  8 KB
  const int MB = (Bsz * Tsz) / 128;  // 256 M-tiles
  int bm = blockIdx.x & (MB - 1);
  int bn = blockIdx.x >> 8;          // 0..7
  int t = threadIdx.x;
  int tx = t & 15, ty = t >> 4;

  float acc[8][4];
#pragma unroll
  for (int r = 0; r < 8; r++)
#pragma unroll
    for (int c = 0; c < 4; c++) acc[r][c] = 0.f;

  const float* Xb = X + (size_t)bm * 128 * K;
  const float* Ub = U + bn * 64;

  for (int k0 = 0; k0 < K; k0 += 32) {
    // A tile: 128 rows x 32 k -> As[kk][m]
    int ar = t >> 3, aq = t & 7;
#pragma unroll
    for (int i = 0; i < 4; i++) {
      int row = ar + 32 * i;
      float4 v = *(const float4*)&Xb[(size_t)row * K + k0 + 4 * aq];
      As[4 * aq + 0][row] = v.x;
      As[4 * aq + 1][row] = v.y;
      As[4 * aq + 2][row] = v.z;
      As[4 * aq + 3][row] = v.w;
    }
    // B tile: 32 k x 64 cols -> Bs[kk][n]
    int bkk = t >> 4, bq = t & 15;
#pragma unroll
    for (int i = 0; i < 2; i++) {
      int kk = bkk + 16 * i;
      *(float4*)&Bs[kk][4 * bq] = *(const float4*)&Ub[(size_t)(k0 + kk) * N + 4 * bq];
    }
    __syncthreads();
#pragma unroll
    for (int kk = 0; kk < 32; kk++) {
      float4 A0 = *(const float4*)&As[kk][ty * 8];
      float4 A1 = *(const float4*)&As[kk][ty * 8 + 4];
      float4 B0 = *(const float4*)&Bs[kk][tx * 4];
      float av[8] = {A0.x, A0.y, A0.z, A0.w, A1.x, A1.y, A1.z, A1.w};
      float bv[4] = {B0.x, B0.y, B0.z, B0.w};
#pragma unroll
      for (int r = 0; r < 8; r++)
#pragma unroll
        for (int c = 0; c < 4; c++) acc[r][c] += av[r] * bv[c];
    }
    __syncthreads();
  }

  float4 bias4 = *(const float4*)&bias[bn * 64 + tx * 4];
  float bb[4] = {bias4.x, bias4.y, bias4.z, bias4.w};
#pragma unroll
  for (int r = 0; r < 8; r++) {
    float4 o;
    o.x = acc[r][0] + bb[0];
    o.y = acc[r][1] + bb[1];
    o.z = acc[r][2] + bb[2];
    o.w = acc[r][3] + bb[3];
    *(float4*)&out[((size_t)bm * 128 + ty * 8 + r) * N + bn * 64 + tx * 4] = o;
  }
}

// ---------------- Phase 2: sequential recurrence ----------------
// h_{t+1} = tanh(xU_t + h_t @ V), done in-place on `out` (holds xU, becomes h).
// 32 groups x 8 blocks. Group g owns batches {2g, 2g+1}; block j in group owns
// V columns [64j, 64j+64), kept in REGISTERS (32 float4/thread). Each step the
// 8 blocks exchange their 64-col slice of h via a global double buffer with a
// per-group atomic flag (device scope). Group members share bid%8 so they
// co-locate on one XCD (perf heuristic; fences make it correct regardless).
// Grid 256 blocks @ 1 block/CU -> all co-resident -> spin sync cannot deadlock.
__global__ __launch_bounds__(512, 2) void p2_rnn(const float* __restrict__ h0,
                                                 const float* __restrict__ V,
                                                 float* __restrict__ out,
                                                 float* __restrict__ ws) {
  int* flags = (int*)ws;           // 32 ints, memset to 0 at launch
  float* hbuf = ws + 64;           // [2][64][512] floats, double buffer

  int bid = blockIdx.x;
  int c = bid & 7, m = bid >> 3;
  int g = c + 8 * (m & 3);         // group 0..31
  int j = m >> 2;                  // column-block 0..7

  int t = threadIdx.x;
  int w = t >> 6;                  // wave 0..7
  int bi = w & 1;                  // batch within group (wave-uniform)
  int kh = w >> 1;                 // K-split 0..3 (wave-uniform)
  int nl = t & 63;
  int ncol = j * 64 + nl;

  __shared__ float h_lds[2][Hsz];  // 4 KB
  __shared__ float red[4][2][64];  // 2 KB

  // V column `ncol`, rows kh*128..+127 -> 32 float4 in registers (128 VGPR)
  float4 Vr[32];
#pragma unroll
  for (int i = 0; i < 32; i++) {
    int k = kh * 128 + 4 * i;
    float4 v;
    v.x = V[(size_t)(k + 0) * Hsz + ncol];
    v.y = V[(size_t)(k + 1) * Hsz + ncol];
    v.z = V[(size_t)(k + 2) * Hsz + ncol];
    v.w = V[(size_t)(k + 3) * Hsz + ncol];
    Vr[i] = v;
  }
  // initial h from h0
  {
    int idx = t * 2;
    int b3 = idx >> 9, k3 = idx & 511;
    *(float2*)&h_lds[b3][k3] = *(const float2*)&h0[(size_t)(2 * g + b3) * Hsz + k3];
  }
  __syncthreads();

  bool owner = (t < 128);          // threads that finalize outputs
  int obi = (t >> 6) & 1;
  int on = t & 63;
  size_t obase = ((size_t)(2 * g + obi) * Tsz) * Hsz + (size_t)(j * 64 + on);
  float xu_cur = owner ? out[obase] : 0.f;  // xU[b][0][ncol]

  for (int s = 0; s < Tsz; s++) {
    // prefetch next step's xU early (hides HBM latency under the FMA phase)
    float xu_next = 0.f;
    if (owner && s < Tsz - 1) xu_next = out[obase + (size_t)(s + 1) * Hsz];

    // partial dot: acc = sum_{k in kh-range} h[bi][k] * V[k][ncol]
    float a0 = 0.f, a1 = 0.f, a2 = 0.f, a3 = 0.f;
#pragma unroll
    for (int i = 0; i < 32; i++) {
      float4 h4 = *(const float4*)&h_lds[bi][kh * 128 + 4 * i];  // wave-broadcast
      a0 += h4.x * Vr[i].x;
      a1 += h4.y * Vr[i].y;
      a2 += h4.z * Vr[i].z;
      a3 += h4.w * Vr[i].w;
    }
    red[kh][bi][nl] = (a0 + a1) + (a2 + a3);
    __syncthreads();

    if (owner) {
      float sum = red[0][obi][on] + red[1][obi][on] + red[2][obi][on] +
                  red[3][obi][on] + xu_cur;
      float hval = tanhf(sum);
      out[obase + (size_t)s * Hsz] = hval;  // in-place: overwrites consumed xU
      if (s < Tsz - 1)
        hbuf[(size_t)((s + 1) & 1) * Bsz * Hsz + (size_t)(2 * g + obi) * Hsz +
             (j * 64 + on)] = hval;
    }
    xu_cur = xu_next;

    if (s < Tsz - 1) {
      __syncthreads();  // all owners' hbuf stores issued
      if (t == 0) {
        __threadfence();                 // make our slice visible (agent scope)
        atomicAdd(&flags[g], 1);         // device-scope by default
        int target = 8 * (s + 1);
        int guard = 0;
        while (__hip_atomic_load(&flags[g], __ATOMIC_RELAXED,
                                 __HIP_MEMORY_SCOPE_AGENT) < target) {
          if (++guard > (1 << 24)) break;  // anti-hang: fail loud, not silent
        }
        __threadfence();                 // invalidate stale L1/L2 before reads
      }
      __syncthreads();
      // reload full h (both batches, all 512 cols) from the just-filled buffer
      {
        int idx = t * 2;
        int b3 = idx >> 9, k3 = idx & 511;
        *(float2*)&h_lds[b3][k3] =
            *(const float2*)&hbuf[(size_t)((s + 1) & 1) * Bsz * Hsz +
                                  (size_t)(2 * g + b3) * Hsz + k3];
      }
      __syncthreads();
    }
  }
}

extern "C" void kernel_launch(void* const* d_in, const int* in_sizes, int n_in,
                              void* d_out, int out_size, void* d_ws, size_t ws_size,
                              hipStream_t stream) {
  const float* x  = (const float*)d_in[0];
  const float* h0 = (const float*)d_in[1];
  const float* U  = (const float*)d_in[2];
  const float* V  = (const float*)d_in[3];
  const float* b  = (const float*)d_in[4];
  float* out = (float*)d_out;
  float* ws  = (float*)d_ws;

  // zero the 32 group flags (d_ws is re-poisoned to 0xAA before every launch)
  hipMemsetAsync(d_ws, 0, 256, stream);

  // Phase 1: out = x @ U + b   (grid: 256 M-tiles x 8 N-tiles)
  p1_gemm<<<dim3(2048), dim3(256), 0, stream>>>(x, U, b, out);

  // Phase 2: in-place recurrence over T
  p2_rnn<<<dim3(256), dim3(512), 0, stream>>>(h0, V, out, ws);
}

// Round 2
// 7141.149 us; speedup vs baseline: 1.2269x; 1.2269x over previous
//
#include <hip/hip_runtime.h>
#include <hip/hip_bf16.h>

#define Bsz 64
#define Tsz 512
#define Isz 512
#define Hsz 512

// ---------------- Phase 1: xU = x @ U + bias ----------------
// M = B*T = 32768, K = 512, N = 512. Tile 128x64, BK=32, 256 threads, 8x4 micro.
__global__ __launch_bounds__(256) void p1_gemm(const float* __restrict__ X,
                                               const float* __restrict__ U,
                                               const float* __restrict__ bias,
                                               float* __restrict__ out) {
  const int K = Isz, N = Hsz;
  __shared__ float As[32][128];   // [kk][m], 16 KB
  __shared__ float Bs[32][64];    // [kk][n],  8 KB
  const int MB = (Bsz * Tsz) / 128;  // 256 M-tiles
  int bm = blockIdx.x & (MB - 1);
  int bn = blockIdx.x >> 8;          // 0..7
  int t = threadIdx.x;
  int tx = t & 15, ty = t >> 4;

  float acc[8][4];
#pragma unroll
  for (int r = 0; r < 8; r++)
#pragma unroll
    for (int c = 0; c < 4; c++) acc[r][c] = 0.f;

  const float* Xb = X + (size_t)bm * 128 * K;
  const float* Ub = U + bn * 64;

  for (int k0 = 0; k0 < K; k0 += 32) {
    int ar = t >> 3, aq = t & 7;
#pragma unroll
    for (int i = 0; i < 4; i++) {
      int row = ar + 32 * i;
      float4 v = *(const float4*)&Xb[(size_t)row * K + k0 + 4 * aq];
      As[4 * aq + 0][row] = v.x;
      As[4 * aq + 1][row] = v.y;
      As[4 * aq + 2][row] = v.z;
      As[4 * aq + 3][row] = v.w;
    }
    int bkk = t >> 4, bq = t & 15;
#pragma unroll
    for (int i = 0; i < 2; i++) {
      int kk = bkk + 16 * i;
      *(float4*)&Bs[kk][4 * bq] = *(const float4*)&Ub[(size_t)(k0 + kk) * N + 4 * bq];
    }
    __syncthreads();
#pragma unroll
    for (int kk = 0; kk < 32; kk++) {
      float4 A0 = *(const float4*)&As[kk][ty * 8];
      float4 A1 = *(const float4*)&As[kk][ty * 8 + 4];
      float4 B0 = *(const float4*)&Bs[kk][tx * 4];
      float av[8] = {A0.x, A0.y, A0.z, A0.w, A1.x, A1.y, A1.z, A1.w};
      float bv[4] = {B0.x, B0.y, B0.z, B0.w};
#pragma unroll
      for (int r = 0; r < 8; r++)
#pragma unroll
        for (int c = 0; c < 4; c++) acc[r][c] += av[r] * bv[c];
    }
    __syncthreads();
  }

  float4 bias4 = *(const float4*)&bias[bn * 64 + tx * 4];
  float bb[4] = {bias4.x, bias4.y, bias4.z, bias4.w};
#pragma unroll
  for (int r = 0; r < 8; r++) {
    float4 o;
    o.x = acc[r][0] + bb[0];
    o.y = acc[r][1] + bb[1];
    o.z = acc[r][2] + bb[2];
    o.w = acc[r][3] + bb[3];
    *(float4*)&out[((size_t)bm * 128 + ty * 8 + r) * N + bn * 64 + tx * 4] = o;
  }
}

// ---------------- Phase 2: sequential recurrence, V in LDS ----------------
// 16 groups x 16 blocks. Group g owns batches 4g..4g+3. Block j stages
// V[:, 32j..32j+31] (64 KB fp32) into dynamic LDS ONCE (XOR-swizzled so the
// per-column ds_read_b128 stream is bank-conflict-free), then reuses it for
// 512 steps. h (4x512) also in LDS, same swizzle. Each thread: 1 column,
// k-range 32, all 4 batches in regs (V element read once, reused x4).
// k-split 16 -> 4-stage __shfl_xor reduce, lane ks==0 finalizes.
// Cross-block h exchange: per-block release flags + global double buffer.
// Group members share bid&15 -> same bid%8 -> likely same XCD (perf only).
#define NG   16
#define NBG  16
#define CPB  32
#define BPG  4
#define HOFF (CPB * Hsz)  // float offset of h region in dynamic LDS

__global__ __launch_bounds__(512) void p2_rnn(const float* __restrict__ h0,
                                              const float* __restrict__ V,
                                              float* __restrict__ out,
                                              float* __restrict__ ws) {
  extern __shared__ float smem[];  // [CPB*512] V + [BPG*512] h = 73728 B
  int* flags = (int*)ws;           // NG*NBG ints, memset to 0 at launch
  float* hbuf = ws + 256;          // [2][Bsz][Hsz] floats, double buffer

  int bid = blockIdx.x;
  int g = bid & (NG - 1);          // group: same bid%8 for all members
  int j = bid >> 4;                // column-block 0..15
  int t = threadIdx.x;
  int c = t >> 4;                  // column 0..31
  int ks = t & 15;                 // k-split 0..15
  int lane = t & 63;

  // ---- stage V[:, 32j + c'] into LDS, swizzled: fidx = c'*512 + (k ^ ((k>>5&7)<<2))
  for (int lin = t; lin < CPB * Hsz; lin += 512) {
    int k = lin >> 5;              // 0..511
    int cc = lin & 31;
    float v = V[(size_t)k * Hsz + CPB * j + cc];
    smem[cc * Hsz + (k ^ (((k >> 5) & 7) << 2))] = v;
  }
  // ---- initial h from h0 (batches 4g..4g+3), swizzled
  for (int lin = t; lin < BPG * Hsz; lin += 512) {
    int b = lin >> 9, k = lin & 511;
    smem[HOFF + b * Hsz + (k ^ (((k >> 5) & 7) << 2))] =
        h0[(size_t)(BPG * g + b) * Hsz + k];
  }
  __syncthreads();

  bool owner = (ks == 0);
  int col = CPB * j + c;
  // xu/out base for this owner's column (batch b adds b*T*H)
  size_t obase = (size_t)(BPG * g) * Tsz * Hsz + col;
  float xu[BPG];
  if (owner) {
#pragma unroll
    for (int b = 0; b < BPG; b++) xu[b] = out[obase + (size_t)b * Tsz * Hsz];
  }

  const int kbase = ks * 32;
  const int sw = (ks & 7) << 2;

  for (int s = 0; s < Tsz; s++) {
    // prefetch next step's xU early (hides HBM/L2 latency under the FMAs)
    float xun[BPG];
    if (owner && s < Tsz - 1) {
#pragma unroll
      for (int b = 0; b < BPG; b++)
        xun[b] = out[obase + (size_t)b * Tsz * Hsz + (size_t)(s + 1) * Hsz];
    }

    // partial dots: acc[b] = sum_{k in [kbase,kbase+32)} h[b][k] * V[k][col]
    float a0 = 0.f, a1 = 0.f, a2 = 0.f, a3 = 0.f;
#pragma unroll
    for (int i = 0; i < 8; i++) {
      int kf = kbase + ((4 * i) ^ sw);  // swizzled float offset
      float4 v = *(const float4*)&smem[c * Hsz + kf];
      float4 h0v = *(const float4*)&smem[HOFF + 0 * Hsz + kf];
      float4 h1v = *(const float4*)&smem[HOFF + 1 * Hsz + kf];
      float4 h2v = *(const float4*)&smem[HOFF + 2 * Hsz + kf];
      float4 h3v = *(const float4*)&smem[HOFF + 3 * Hsz + kf];
      a0 += v.x * h0v.x + v.y * h0v.y + v.z * h0v.z + v.w * h0v.w;
      a1 += v.x * h1v.x + v.y * h1v.y + v.z * h1v.z + v.w * h1v.w;
      a2 += v.x * h2v.x + v.y * h2v.y + v.z * h2v.z + v.w * h2v.w;
      a3 += v.x * h3v.x + v.y * h3v.y + v.z * h3v.z + v.w * h3v.w;
    }
    // reduce over the 16 k-split lanes (within each 16-lane group)
#pragma unroll
    for (int m = 1; m < 16; m <<= 1) {
      a0 += __shfl_xor(a0, m);
      a1 += __shfl_xor(a1, m);
      a2 += __shfl_xor(a2, m);
      a3 += __shfl_xor(a3, m);
    }

    int p = (s + 1) & 1;
    if (owner) {
      float hv[BPG];
      hv[0] = tanhf(a0 + xu[0]);
      hv[1] = tanhf(a1 + xu[1]);
      hv[2] = tanhf(a2 + xu[2]);
      hv[3] = tanhf(a3 + xu[3]);
#pragma unroll
      for (int b = 0; b < BPG; b++) {
        out[obase + (size_t)b * Tsz * Hsz + (size_t)s * Hsz] = hv[b];
        if (s < Tsz - 1) hbuf[p * Bsz * Hsz + (BPG * g + b) * Hsz + col] = hv[b];
      }
    }
#pragma unroll
    for (int b = 0; b < BPG; b++) xu[b] = xun[b];

    if (s < Tsz - 1) {
      __syncthreads();  // all owners' hbuf stores issued
      if (t == 0) {
        __threadfence();  // make our slice visible device-wide
        __hip_atomic_store(&flags[g * NBG + j], s + 1, __ATOMIC_RELAXED,
                           __HIP_MEMORY_SCOPE_AGENT);
      }
      if (t < 64) {  // wave 0: 16 lanes poll 16 per-block flags in parallel
        int target = s + 1;
        int guard = 0;
        while (true) {
          int f = (lane < NBG)
                      ? __hip_atomic_load(&flags[g * NBG + lane], __ATOMIC_RELAXED,
                                          __HIP_MEMORY_SCOPE_AGENT)
                      : target;
          if (__all(f >= target)) break;
          if (++guard > (1 << 24)) break;  // anti-hang: fail loud, not silent
        }
        __threadfence();  // invalidate stale caches before hbuf reads
      }
      __syncthreads();
      // copy group h (4x512 = 8 KB) from the just-filled buffer into LDS
      {
        int lin = t * 4;  // one float4 per thread
        int b = lin >> 9, k = lin & 511;
        float4 hv = *(const float4*)&hbuf[p * Bsz * Hsz + (BPG * g + b) * Hsz + k];
        *(float4*)&smem[HOFF + b * Hsz + (k ^ (((k >> 5) & 7) << 2))] = hv;
      }
      __syncthreads();
    }
  }
}

extern "C" void kernel_launch(void* const* d_in, const int* in_sizes, int n_in,
                              void* d_out, int out_size, void* d_ws, size_t ws_size,
                              hipStream_t stream) {
  const float* x  = (const float*)d_in[0];
  const float* h0 = (const float*)d_in[1];
  const float* U  = (const float*)d_in[2];
  const float* V  = (const float*)d_in[3];
  const float* b  = (const float*)d_in[4];
  float* out = (float*)d_out;
  float* ws  = (float*)d_ws;

  // 72 KB dynamic LDS for p2 (V slice 64 KB + h 8 KB)
  static const int kDynLds = (CPB * Hsz + BPG * Hsz) * 4;
  hipFuncSetAttribute(reinterpret_cast<const void*>(p2_rnn),
                      hipFuncAttributeMaxDynamicSharedMemorySize, kDynLds);

  // zero the 256 per-block flags (ws is re-poisoned to 0xAA before every launch)
  hipMemsetAsync(d_ws, 0, NG * NBG * sizeof(int), stream);

  // Phase 1: out = x @ U + b
  p1_gemm<<<dim3(2048), dim3(256), 0, stream>>>(x, U, b, out);

  // Phase 2: in-place recurrence over T
  p2_rnn<<<dim3(256), dim3(512), kDynLds, stream>>>(h0, V, out, ws);
}